// Round 9
// baseline (79.554 us; speedup 1.0000x reference)
//
#include <hip/hip_runtime.h>
#include <hip/hip_bf16.h>

#define C_IN 1024
#define T_SZ 128
#define CTX 64
#define NEV 16
#define NTILE 16     // C_IN / 64
#define NTHR 512
#define BROW 72      // bf16 row stride (144 B: 16B-aligned, 4-bank-rotating)
#define PLROW 132    // padded P dump row stride (f32 elems)

// arena layout (bytes)
#define BF_OFF 0                 // Bf: 8 waves * 2 buf * 16 * 72 * 2 = 36864
#define WS_OFF 36864             // wswl: 1024*4 = 4096
#define AT_OFF 40960             // attn: 128*4
#define TV_OFF 41472             // topv
#define TI_OFF 41536             // topi
#define ARENA_SZ 41600
// P dump overlays [0, 33792) after the loop (Bf/wswl dead; attn+ live above 40960)

typedef short bf16x8 __attribute__((ext_vector_type(8)));
typedef float f32x4 __attribute__((ext_vector_type(4)));

__device__ __forceinline__ unsigned short f2bf(float f) {
  __hip_bfloat16 h = __float2bfloat16(f);
  return *(unsigned short*)&h;
}

// enc: thread (cg,tp) loads float2 at [kt*64 + cg*8 + j][n0 + 2tp] — 8x64B lines/instr
#define ISSUE_E(kt, ev) do { \
  const float* _s = encB + ((kt) * 64 + cg * 8) * T_SZ + n0 + 2 * tp; \
  _Pragma("unroll") for (int _j = 0; _j < 8; ++_j) \
    ev[_j] = *(const float2*)(_s + _j * T_SZ); \
} while (0)

// W: lane (g,tl) loads its A-frag rows directly from global (L2-resident)
#define ISSUE_W(kt) do { \
  _Pragma("unroll") for (int _a = 0; _a < 4; ++_a) \
  _Pragma("unroll") for (int _k = 0; _k < 2; ++_k) { \
    const float* _w = wvec + (_a * 16 + tl) * C_IN + (kt) * 64 + _k * 32 + g * 8; \
    wW[(_a * 2 + _k) * 2 + 0] = *(const float4*)_w; \
    wW[(_a * 2 + _k) * 2 + 1] = *(const float4*)(_w + 4); \
  } } while (0)

// exact-f32 switch partial + bf16 convert + wave-private LDS write-transpose
#define CVTWRITE(kt, ev, buf) do { \
  const float* _wt = wswl + (kt) * 64 + cg * 8; \
  union { bf16x8 v; unsigned short u[8]; } _p0, _p1; \
  _Pragma("unroll") for (int _j = 0; _j < 8; ++_j) { \
    sw0 = fmaf(ev[_j].x, _wt[_j], sw0); \
    sw1 = fmaf(ev[_j].y, _wt[_j], sw1); \
    _p0.u[_j] = f2bf(ev[_j].x); \
    _p1.u[_j] = f2bf(ev[_j].y); \
  } \
  *(bf16x8*)&BfW[((buf) * 16 + 2 * tp    ) * BROW + cg * 8] = _p0.v; \
  *(bf16x8*)&BfW[((buf) * 16 + 2 * tp + 1) * BROW + cg * 8] = _p1.v; \
} while (0)

#define MF1(_k, AIDX, ACC, BV) do { \
  union { bf16x8 v; unsigned short u[8]; } _pa; \
  float4 _w0 = wW[(AIDX * 2 + _k) * 2], _w1 = wW[(AIDX * 2 + _k) * 2 + 1]; \
  _pa.u[0] = f2bf(_w0.x); _pa.u[1] = f2bf(_w0.y); _pa.u[2] = f2bf(_w0.z); _pa.u[3] = f2bf(_w0.w); \
  _pa.u[4] = f2bf(_w1.x); _pa.u[5] = f2bf(_w1.y); _pa.u[6] = f2bf(_w1.z); _pa.u[7] = f2bf(_w1.w); \
  ACC = __builtin_amdgcn_mfma_f32_16x16x32_bf16(_pa.v, BV, ACC, 0, 0, 0); \
} while (0)

#define COMPUTE(buf) do { \
  _Pragma("unroll") for (int _k = 0; _k < 2; ++_k) { \
    bf16x8 _bv = *(const bf16x8*)&BfW[((buf) * 16 + tl) * BROW + _k * 32 + g * 8]; \
    MF1(_k, 0, acc0, _bv); \
    MF1(_k, 1, acc1, _bv); \
    MF1(_k, 2, acc2, _bv); \
    MF1(_k, 3, acc3, _bv); \
  } } while (0)

// step T: issue W(T) + enc(T+2) into slot SA; convert enc(T+1) from slot SB; compute T.
// All deps are same-wave: NO barrier.
#define STEP(T, SA, SB) do { \
  ISSUE_W(T); \
  if ((T) + 2 < NTILE) ISSUE_E((T) + 2, ev##SA); \
  if ((T) + 1 < NTILE) CVTWRITE((T) + 1, ev##SB, ((T) + 1) & 1); \
  COMPUTE((T) & 1); \
} while (0)

__global__ __launch_bounds__(NTHR, 1) void fused_sparsify(
    const float* __restrict__ enc,   // [256][1024][128] f32
    const float* __restrict__ wvec,  // [64][1024] f32
    const float* __restrict__ bvec,  // [64] f32
    const float* __restrict__ wsw,   // [1024] f32
    const float* __restrict__ bsw,   // [1] f32
    float* __restrict__ out)         // vecs [256*16*64] ++ sched [256*16*128], f32
{
  const int b    = blockIdx.x;
  const int tid  = threadIdx.x;
  const int lane = tid & 63;
  const int wid  = tid >> 6;   // wave 0..7
  const int g    = lane >> 4;  // MFMA k-group 0..3
  const int tl   = lane & 15;  // MFMA row/col lane
  const int n0   = wid * 16;   // this wave's t-slice (staging AND output)
  const int cg   = lane >> 3;  // staging c-group 0..7
  const int tp   = lane & 7;   // staging t-pair 0..7

  __shared__ __align__(16) char arena[ARENA_SZ];
  unsigned short* Bf   = (unsigned short*)(arena + BF_OFF);
  unsigned short* BfW  = Bf + wid * (2 * 16 * BROW);   // wave-private double buffer
  float* wswl = (float*)(arena + WS_OFF);
  float* attn = (float*)(arena + AT_OFF);
  float* topv = (float*)(arena + TV_OFF);
  int*   topi = (int*)(arena + TI_OFF);

  const float* encB = enc + (size_t)b * (C_IN * T_SZ);
  const float bsw0 = bsw[0];

  f32x4 acc0 = {0.f, 0.f, 0.f, 0.f};
  f32x4 acc1 = acc0, acc2 = acc0, acc3 = acc0;
  float sw0 = 0.f, sw1 = 0.f;

  float2 evA[8], evB[8];
  float4 wW[16];

  // ---------- prologue ----------
  ISSUE_E(0, evA);
  ISSUE_E(1, evB);
  wswl[tid]       = wsw[tid];
  wswl[tid + 512] = wsw[tid + 512];
  __syncthreads();             // publish wswl (the only block-wide barrier pre-epilogue)
  CVTWRITE(0, evA, 0);

  // ---------- 16 self-paced steps, zero barriers ----------
  STEP( 0, A, B); STEP( 1, B, A); STEP( 2, A, B); STEP( 3, B, A);
  STEP( 4, A, B); STEP( 5, B, A); STEP( 6, A, B); STEP( 7, B, A);
  STEP( 8, A, B); STEP( 9, B, A); STEP(10, A, B); STEP(11, B, A);
  STEP(12, A, B); STEP(13, B, A); STEP(14, A, B); STEP(15, B, A);

  // ---------- switch: reduce over cg lanes (exact f32), bias+relu ----------
  sw0 += __shfl_xor(sw0, 8, 64);  sw1 += __shfl_xor(sw1, 8, 64);
  sw0 += __shfl_xor(sw0, 16, 64); sw1 += __shfl_xor(sw1, 16, 64);
  sw0 += __shfl_xor(sw0, 32, 64); sw1 += __shfl_xor(sw1, 32, 64);
  if (cg == 0) {
    attn[n0 + 2 * tp]     = fmaxf(sw0 + bsw0, 0.f);
    attn[n0 + 2 * tp + 1] = fmaxf(sw1 + bsw0, 0.f);
  }
  __syncthreads();

  // ---------- P dump (overlays Bf/wswl, dead now) ----------
  float* Pl = (float*)(arena + BF_OFF);    // [64][PLROW] f32 = 33792 B
#pragma unroll
  for (int r = 0; r < 4; ++r) {
    Pl[( 0 + 4 * g + r) * PLROW + n0 + tl] = acc0[r];
    Pl[(16 + 4 * g + r) * PLROW + n0 + tl] = acc1[r];
    Pl[(32 + 4 * g + r) * PLROW + n0 + tl] = acc2[r];
    Pl[(48 + 4 * g + r) * PLROW + n0 + tl] = acc3[r];
  }
  __syncthreads();

  // ---------- top-16 descending, ties -> lower index (wave 0) ----------
  if (tid < 64) {
    float v0 = attn[tid], v1 = attn[tid + 64];
#pragma unroll 1
    for (int r = 0; r < NEV; ++r) {
      float bv; int bi;
      if (v0 >= v1) { bv = v0; bi = tid; } else { bv = v1; bi = tid + 64; }
#pragma unroll
      for (int off = 32; off > 0; off >>= 1) {
        float ov = __shfl_xor(bv, off, 64);
        int   oi = __shfl_xor(bi, off, 64);
        if (ov > bv || (ov == bv && oi < bi)) { bv = ov; bi = oi; }
      }
      if (bi == tid) v0 = -__builtin_inff();
      if (bi == tid + 64) v1 = -__builtin_inff();
      if (tid == r) { topv[r] = bv; topi[r] = bi; }
    }
  }
  __syncthreads();

  // ---------- scheduling: out[262144 + b*2048 + j*128 + t] ----------
  {
    float* os = out + (256 * NEV * CTX) + b * (NEV * T_SZ);
    int j  = tid >> 5;
    int tt = (tid * 4) & 127;
    float tv = topv[j];
    int   ti = topi[j];
    float4 v;
    v.x = (tt + 0 == ti) ? tv : 0.f;
    v.y = (tt + 1 == ti) ? tv : 0.f;
    v.z = (tt + 2 == ti) ? tv : 0.f;
    v.w = (tt + 3 == ti) ? tv : 0.f;
    *(float4*)&os[tid * 4] = v;
  }
  // ---------- vecs: out[b*1024 + j*64 + d] = P[d][idx[j]] + b_vec[d] ----------
  {
    float* ov = out + b * (NEV * CTX);
#pragma unroll
    for (int s = 0; s < 2; ++s) {
      int o = s * NTHR + tid;
      int j = o >> 6, d = o & 63;
      ov[o] = Pl[d * PLROW + topi[j]] + bvec[d];
    }
  }
}

extern "C" void kernel_launch(void* const* d_in, const int* in_sizes, int n_in,
                              void* d_out, int out_size, void* d_ws, size_t ws_size,
                              hipStream_t stream) {
  const float* enc  = (const float*)d_in[0];
  const float* wvec = (const float*)d_in[1];
  const float* bvec = (const float*)d_in[2];
  const float* wsw  = (const float*)d_in[3];
  const float* bsw  = (const float*)d_in[4];
  float* o = (float*)d_out;
  (void)in_sizes; (void)n_in; (void)out_size; (void)d_ws; (void)ws_size;
  fused_sparsify<<<256, NTHR, 0, stream>>>(enc, wvec, bvec, wsw, bsw, o);
}

// Round 10
// 35.139 us; speedup vs baseline: 2.2640x; 2.2640x over previous
//
#include <hip/hip_runtime.h>
#include <hip/hip_bf16.h>

#define C_IN 1024
#define T_SZ 128
#define CTX 64
#define NEV 16
#define BK 64
#define NTILE 16     // C_IN / BK
#define NTHR 512
#define BROW 72      // bf16 row stride (144 B: 16B-aligned, bank-uniform)
#define PLROW 132    // padded P dump row stride (f32 elems)

// arena layout (bytes)
#define BF_OFF 0                 // Bf: 2*128*72*2 = 36864
#define WB_OFF 36864             // Wb: 2*64*72*2  = 18432
#define WS_OFF 55296             // wswl: 1024*4   = 4096
#define SP_OFF 59392             // swp: 8*128*4   = 4096
#define AT_OFF 63488             // attn: 128*4
#define TV_OFF 64000             // topv
#define TI_OFF 64064             // topi
#define ARENA_SZ 64128

typedef short bf16x8 __attribute__((ext_vector_type(8)));
typedef float f32x4 __attribute__((ext_vector_type(4)));
typedef float f32x2 __attribute__((ext_vector_type(2)));

__device__ __forceinline__ unsigned short f2bf(float f) {
  __hip_bfloat16 h = __float2bfloat16(f);
  return *(unsigned short*)&h;
}

#define BARRIER() do { \
  asm volatile("s_waitcnt lgkmcnt(0)" ::: "memory"); \
  __builtin_amdgcn_s_barrier(); \
} while (0)

// load enc tile kt slice (8 c x 2 t per thread, coalesced 512B/instr, NT to skip L1)
// + W tile slice (cached: L2-resident, reused across blocks)
#define ISSUE(kt, ev, wv) do { \
  const float* _s = encB + (kt) * (BK * T_SZ) + cb0 * T_SZ + t0; \
  _Pragma("unroll") for (int _j = 0; _j < 8; ++_j) \
    ev[_j] = __builtin_nontemporal_load((const f32x2*)(_s + _j * T_SZ)); \
  const float* _w = wvec + wd * C_IN + (kt) * BK + wc; \
  wv[0] = *(const float4*)_w; \
  wv[1] = *(const float4*)(_w + 4); \
} while (0)

// switch partial (exact f32) + convert to bf16 + write B/W fragments to LDS
#define CONVERT(kt, ev, wv, buf) do { \
  const float* _wt = wswl + (kt) * BK + cb0; \
  union { bf16x8 v; unsigned short u[8]; } _p0, _p1, _pw; \
  _Pragma("unroll") for (int _j = 0; _j < 8; ++_j) { \
    sw0 = fmaf(ev[_j].x, _wt[_j], sw0); \
    sw1 = fmaf(ev[_j].y, _wt[_j], sw1); \
    _p0.u[_j] = f2bf(ev[_j].x); \
    _p1.u[_j] = f2bf(ev[_j].y); \
  } \
  *(bf16x8*)&Bf[((buf) * T_SZ + t0) * BROW + cb0] = _p0.v; \
  *(bf16x8*)&Bf[((buf) * T_SZ + t0 + 1) * BROW + cb0] = _p1.v; \
  _pw.u[0] = f2bf(wv[0].x); _pw.u[1] = f2bf(wv[0].y); \
  _pw.u[2] = f2bf(wv[0].z); _pw.u[3] = f2bf(wv[0].w); \
  _pw.u[4] = f2bf(wv[1].x); _pw.u[5] = f2bf(wv[1].y); \
  _pw.u[6] = f2bf(wv[1].z); _pw.u[7] = f2bf(wv[1].w); \
  *(bf16x8*)&Wb[((buf) * CTX + wd) * BROW + wc] = _pw.v; \
} while (0)

#define MFMA_TILE(buf) do { \
  _Pragma("unroll") for (int _ks = 0; _ks < 2; ++_ks) { \
    bf16x8 _bv = *(const bf16x8*)&Bf[((buf) * T_SZ + n0 + tl) * BROW + _ks * 32 + g * 8]; \
    bf16x8 _a0 = *(const bf16x8*)&Wb[((buf) * CTX +  0 + tl) * BROW + _ks * 32 + g * 8]; \
    bf16x8 _a1 = *(const bf16x8*)&Wb[((buf) * CTX + 16 + tl) * BROW + _ks * 32 + g * 8]; \
    bf16x8 _a2 = *(const bf16x8*)&Wb[((buf) * CTX + 32 + tl) * BROW + _ks * 32 + g * 8]; \
    bf16x8 _a3 = *(const bf16x8*)&Wb[((buf) * CTX + 48 + tl) * BROW + _ks * 32 + g * 8]; \
    acc0 = __builtin_amdgcn_mfma_f32_16x16x32_bf16(_a0, _bv, acc0, 0, 0, 0); \
    acc1 = __builtin_amdgcn_mfma_f32_16x16x32_bf16(_a1, _bv, acc1, 0, 0, 0); \
    acc2 = __builtin_amdgcn_mfma_f32_16x16x32_bf16(_a2, _bv, acc2, 0, 0, 0); \
    acc3 = __builtin_amdgcn_mfma_f32_16x16x32_bf16(_a3, _bv, acc3, 0, 0, 0); \
  } } while (0)

// pipeline step: tile T from LDS buf T&1; prefetch T+3 into slot SI (=T%3);
// convert T+1 from slot SC (=(T+1)%3) into buf (T+1)&1. One barrier per tile.
#define STEP(T, SI, SC) do { \
  if ((T) + 3 < NTILE) ISSUE((T) + 3, ev##SI, wv##SI); \
  MFMA_TILE((T) & 1); \
  if ((T) + 1 < NTILE) CONVERT((T) + 1, ev##SC, wv##SC, ((T) + 1) & 1); \
  BARRIER(); \
} while (0)

__global__ __launch_bounds__(NTHR, 1) void fused_sparsify(
    const float* __restrict__ enc,   // [256][1024][128] f32
    const float* __restrict__ wvec,  // [64][1024] f32
    const float* __restrict__ bvec,  // [64] f32
    const float* __restrict__ wsw,   // [1024] f32
    const float* __restrict__ bsw,   // [1] f32
    float* __restrict__ out)         // vecs [256*16*64] ++ sched [256*16*128], f32
{
  const int b    = blockIdx.x;
  const int tid  = threadIdx.x;
  const int lane = tid & 63;
  const int wid  = tid >> 6;   // wave 0..7
  const int g    = lane >> 4;  // k-group 0..3
  const int tl   = lane & 15;
  const int n0   = wid * 16;   // this wave's MFMA t-slice

  // staging geometry: wave = c-block of 8, lane = t-pair
  const int cb0 = wid * 8;     // c offset within tile
  const int t0  = 2 * lane;    // t pair
  const int wd  = tid >> 3;    // W row 0..63
  const int wc  = (tid & 7) * 8;

  __shared__ __align__(16) char arena[ARENA_SZ];
  unsigned short* Bf = (unsigned short*)(arena + BF_OFF);  // [2][128][BROW] bf16
  unsigned short* Wb = (unsigned short*)(arena + WB_OFF);  // [2][64][BROW] bf16
  float* wswl = (float*)(arena + WS_OFF);
  float* swp  = (float*)(arena + SP_OFF);                  // [8][128]
  float* attn = (float*)(arena + AT_OFF);
  float* topv = (float*)(arena + TV_OFF);
  int*   topi = (int*)(arena + TI_OFF);

  const float* encB = enc + (size_t)b * (C_IN * T_SZ);

  f32x4 acc0 = {0.f, 0.f, 0.f, 0.f};
  f32x4 acc1 = acc0, acc2 = acc0, acc3 = acc0;
  float sw0 = 0.f, sw1 = 0.f;

  f32x2 evA[8], evB[8], evC[8];
  float4 wvA[2], wvB[2], wvC[2];

  // ---------- prologue: 3 tiles in flight ----------
  ISSUE(0, evA, wvA);
  ISSUE(1, evB, wvB);
  ISSUE(2, evC, wvC);
  wswl[tid]       = wsw[tid];
  wswl[tid + 512] = wsw[tid + 512];
  BARRIER();                 // publish wswl (tile loads stay in flight)
  CONVERT(0, evA, wvA, 0);
  BARRIER();                 // publish Bf[0], Wb[0]

  // ---------- 16 fully-unrolled steps, slot = t%3, buf = t&1 ----------
  STEP( 0, A, B); STEP( 1, B, C); STEP( 2, C, A);
  STEP( 3, A, B); STEP( 4, B, C); STEP( 5, C, A);
  STEP( 6, A, B); STEP( 7, B, C); STEP( 8, C, A);
  STEP( 9, A, B); STEP(10, B, C); STEP(11, C, A);
  STEP(12, A, B); STEP(13, B, C); STEP(14, C, A);
  MFMA_TILE(1);              // tile 15
  BARRIER();                 // protect Bf before P-dump overlay

  // ---------- epilogue: P dump (overlays Bf, dead) + switch partials ----------
  float* Pl = (float*)(arena + BF_OFF);    // [64][PLROW] f32 = 33792 B
#pragma unroll
  for (int r = 0; r < 4; ++r) {
    Pl[( 0 + 4 * g + r) * PLROW + n0 + tl] = acc0[r];
    Pl[(16 + 4 * g + r) * PLROW + n0 + tl] = acc1[r];
    Pl[(32 + 4 * g + r) * PLROW + n0 + tl] = acc2[r];
    Pl[(48 + 4 * g + r) * PLROW + n0 + tl] = acc3[r];
  }
  swp[wid * T_SZ + t0]     = sw0;
  swp[wid * T_SZ + t0 + 1] = sw1;
  __syncthreads();

  if (tid < T_SZ) {
    float s = 0.f;
#pragma unroll
    for (int k = 0; k < 8; ++k) s += swp[k * T_SZ + tid];
    attn[tid] = fmaxf(s + bsw[0], 0.f);
  }
  __syncthreads();

  // ---------- top-16 descending, ties -> lower index (wave 0) ----------
  if (tid < 64) {
    float v0 = attn[tid], v1 = attn[tid + 64];
#pragma unroll 1
    for (int r = 0; r < NEV; ++r) {
      float bv; int bi;
      if (v0 >= v1) { bv = v0; bi = tid; } else { bv = v1; bi = tid + 64; }
#pragma unroll
      for (int off = 32; off > 0; off >>= 1) {
        float ov = __shfl_xor(bv, off, 64);
        int   oi = __shfl_xor(bi, off, 64);
        if (ov > bv || (ov == bv && oi < bi)) { bv = ov; bi = oi; }
      }
      if (bi == tid) v0 = -__builtin_inff();
      if (bi == tid + 64) v1 = -__builtin_inff();
      if (tid == r) { topv[r] = bv; topi[r] = bi; }
    }
  }
  __syncthreads();

  // ---------- scheduling: out[262144 + b*2048 + j*128 + t] ----------
  {
    float* os = out + (256 * NEV * CTX) + b * (NEV * T_SZ);
    int j  = tid >> 5;
    int tt = (tid * 4) & 127;
    float tv = topv[j];
    int   ti = topi[j];
    float4 v;
    v.x = (tt + 0 == ti) ? tv : 0.f;
    v.y = (tt + 1 == ti) ? tv : 0.f;
    v.z = (tt + 2 == ti) ? tv : 0.f;
    v.w = (tt + 3 == ti) ? tv : 0.f;
    *(float4*)&os[tid * 4] = v;
  }
  // ---------- vecs: out[b*1024 + j*64 + d] = P[d][idx[j]] + b_vec[d] ----------
  {
    float* ov = out + b * (NEV * CTX);
#pragma unroll
    for (int s = 0; s < 2; ++s) {
      int o = s * NTHR + tid;
      int j = o >> 6, d = o & 63;
      ov[o] = Pl[d * PLROW + topi[j]] + bvec[d];
    }
  }
}

extern "C" void kernel_launch(void* const* d_in, const int* in_sizes, int n_in,
                              void* d_out, int out_size, void* d_ws, size_t ws_size,
                              hipStream_t stream) {
  const float* enc  = (const float*)d_in[0];
  const float* wvec = (const float*)d_in[1];
  const float* bvec = (const float*)d_in[2];
  const float* wsw  = (const float*)d_in[3];
  const float* bsw  = (const float*)d_in[4];
  float* o = (float*)d_out;
  (void)in_sizes; (void)n_in; (void)out_size; (void)d_ws; (void)ws_size;
  fused_sparsify<<<256, NTHR, 0, stream>>>(enc, wvec, bvec, wsw, bsw, o);
}